// Round 7
// baseline (381.757 us; speedup 1.0000x reference)
//
#include <hip/hip_runtime.h>

// CALIBRATION ROUND: identical gather kernel to round 4, but launched 5x per
// kernel_launch (idempotent: out[b] = f(inputs), last write wins, validation
// unchanged). Headline dur_us slope vs round 4 measures per-launch cost:
//   dur_us ~= 308 + 4*T_warm.
// This disambiguates "kernel ~5-30us, headline = harness poison fills" from
// "kernel ~150us, real headroom".
//
// HashEmbeddingBag mean-pool: out[b,d] = (1/max(len_b,1)) * sum_{l<len_b} weight[idx[b,l], d]
// weight: [1_000_000, 64] f32, idx: [4096, 200] i32, lengths: [4096] i32, out: [4096, 64] f32.

#define NUM_BUCKETS 1000000
#define DIM 64
#define BAGS 4096
#define LMAX 200

__global__ __launch_bounds__(128, 8) void hashbag_kernel(
    const float* __restrict__ weight,
    const int* __restrict__ idx,
    const int* __restrict__ lengths,
    float* __restrict__ out)
{
    __shared__ int    s_off[LMAX];     // element offsets (idx*64)
    __shared__ float4 s_part[16];      // wave-1 partials

    const int b    = blockIdx.x;
    const int tid  = threadIdx.x;      // 0..127
    const int wave = tid >> 6;         // 0 or 1
    const int lane = tid & 63;
    const int g    = lane >> 4;        // row group 0..3
    const int l16  = lane & 15;        // dim group: dims [l16*4 .. l16*4+3]
    const int len  = lengths[b];

    // Stage indices -> LDS as pre-shifted element offsets (coalesced i32 loads).
    const int* bag = idx + (long)b * LMAX;
    for (int l = tid; l < len; l += 128) {
        s_off[l] = bag[l] << 6;        // idx * DIM
    }
    __syncthreads();

    // This wave's contiguous row range: wave 0 -> [0,hl), wave 1 -> [hl,len).
    const int hl    = (len + 1) >> 1;
    const int start = wave * hl;
    const int end   = (len < start + hl) ? len : (start + hl);

    const float* wbase = weight + (l16 << 2);
    float ax = 0.f, ay = 0.f, az = 0.f, aw = 0.f;

    int r = start + g;                 // group g handles rows start+g, +4, +8, ...
    // Unrolled: 4 independent 1KB row-quad loads in flight (16 rows / 4KB per iter).
    for (; r + 12 < end; r += 16) {
        const int o0 = s_off[r];
        const int o1 = s_off[r + 4];
        const int o2 = s_off[r + 8];
        const int o3 = s_off[r + 12];
        const float4 v0 = *(const float4*)(wbase + o0);
        const float4 v1 = *(const float4*)(wbase + o1);
        const float4 v2 = *(const float4*)(wbase + o2);
        const float4 v3 = *(const float4*)(wbase + o3);
        ax += (v0.x + v1.x) + (v2.x + v3.x);
        ay += (v0.y + v1.y) + (v2.y + v3.y);
        az += (v0.z + v1.z) + (v2.z + v3.z);
        aw += (v0.w + v1.w) + (v2.w + v3.w);
    }
    for (; r < end; r += 4) {
        const float4 v = *(const float4*)(wbase + s_off[r]);
        ax += v.x; ay += v.y; az += v.z; aw += v.w;
    }

    // Reduce across the 4 row-groups (lanes l16, l16+16, l16+32, l16+48).
    ax += __shfl_xor(ax, 16); ay += __shfl_xor(ay, 16);
    az += __shfl_xor(az, 16); aw += __shfl_xor(aw, 16);
    ax += __shfl_xor(ax, 32); ay += __shfl_xor(ay, 32);
    az += __shfl_xor(az, 32); aw += __shfl_xor(aw, 32);

    // Combine the two waves via LDS; wave 0 lanes 0-15 store the row.
    if (wave == 1 && lane < 16) {
        float4 p; p.x = ax; p.y = ay; p.z = az; p.w = aw;
        s_part[l16] = p;
    }
    __syncthreads();
    if (wave == 0 && lane < 16) {
        const float4 p = s_part[l16];
        const float inv = 1.f / (float)((len > 0) ? len : 1);
        float4 o;
        o.x = (ax + p.x) * inv;
        o.y = (ay + p.y) * inv;
        o.z = (az + p.z) * inv;
        o.w = (aw + p.w) * inv;
        *(float4*)(out + b * DIM + (l16 << 2)) = o;   // 256B coalesced store
    }
}

extern "C" void kernel_launch(void* const* d_in, const int* in_sizes, int n_in,
                              void* d_out, int out_size, void* d_ws, size_t ws_size,
                              hipStream_t stream) {
    const float* weight  = (const float*)d_in[0];
    const int*   idx     = (const int*)d_in[1];
    const int*   lengths = (const int*)d_in[2];
    float*       out     = (float*)d_out;

    // 5 identical idempotent launches: headline slope = 4 * per-launch cost.
    #pragma unroll 1
    for (int rep = 0; rep < 5; ++rep) {
        hashbag_kernel<<<BAGS, 128, 0, stream>>>(weight, idx, lengths, out);
    }
}